// Round 2
// baseline (269.319 us; speedup 1.0000x reference)
//
#include <hip/hip_runtime.h>
#include <hip/hip_bf16.h>

typedef __attribute__((ext_vector_type(8))) short s16x8;
typedef __attribute__((ext_vector_type(4))) short s16x4;
typedef __attribute__((ext_vector_type(4))) float f32x4;

#if __has_builtin(__builtin_amdgcn_exp2f)
#define EXP2F(x) __builtin_amdgcn_exp2f(x)
#else
#define EXP2F(x) exp2f(x)
#endif

#define S_LEN 2048
#define EMB   512
#define MROWS 8192   // S*B

__device__ __forceinline__ float bf2f(short x) {
    union { float f; unsigned u; } z; z.u = ((unsigned)(unsigned short)x) << 16; return z.f;
}
// RNE — epilogues only
__device__ __forceinline__ short f2bf(float f) {
    union { float f; unsigned u; } z; z.f = f;
    unsigned r = z.u + 0x7FFF + ((z.u >> 16) & 1);
    return (short)(r >> 16);
}
// fast round-half-away (2 VALU ops) — hot paths
__device__ __forceinline__ short f2bf_fast(float f) {
    union { float f; unsigned u; } z; z.f = f;
    return (short)((z.u + 0x8000u) >> 16);
}

// ---------------------------------------------------------------------------
// BT-GEMM mainloop (512 threads = 8 waves, 4x2 wave grid, wave tile 32x64):
// C[128x128] += A[128xK] * B[128xK]^T.  Double-buffered LDS, one barrier
// per K-step.
// ---------------------------------------------------------------------------
template<int AF32, int BF32>
__device__ __forceinline__ void gemm_mainloop(const void* __restrict__ Ag,
                                              const void* __restrict__ Bg,
                                              short* sA, short* sB,
                                              f32x4 acc[2][4], int K)
{
    const int tid  = threadIdx.x;          // 0..511
    const int lane = tid & 63;
    const int wv   = tid >> 6;             // 0..7
    const int l15  = lane & 15, quad = lane >> 4;
    const int wm   = (wv >> 1) * 32, wn = (wv & 1) * 64;

    f32x4 afr[2], bfr[2];   // fp32 staging regs (2 x f32x4 per tile)
    s16x8 ahr, bhr;         // bf16 staging regs (1 x s16x8 per tile)

    auto loadT = [&](const void* G, int kt, f32x4* fr, s16x8& hr, int F32) {
        if (F32) {
#pragma unroll
            for (int p = 0; p < 2; ++p) {
                int c = tid + p * 512;     // 1024 chunks of 4 floats
                fr[p] = *(const f32x4*)((const float*)G + (size_t)(c >> 3) * K + kt + (c & 7) * 4);
            }
        } else {
            hr = *(const s16x8*)((const short*)G + (size_t)(tid >> 2) * K + kt + (tid & 3) * 8);
        }
    };
    auto commitT = [&](short* s, f32x4* fr, s16x8& hr, int F32) {
        if (F32) {
#pragma unroll
            for (int p = 0; p < 2; ++p) {
                int c = tid + p * 512;
                s16x4 o4;
                o4[0] = f2bf_fast(fr[p][0]); o4[1] = f2bf_fast(fr[p][1]);
                o4[2] = f2bf_fast(fr[p][2]); o4[3] = f2bf_fast(fr[p][3]);
                *(s16x4*)(s + c * 4) = o4;
            }
        } else {
            *(s16x8*)(s + tid * 8) = hr;
        }
    };

    // prologue: stage tile 0 into buffer 0
    loadT(Ag, 0, afr, ahr, AF32);
    loadT(Bg, 0, bfr, bhr, BF32);
    commitT(sA, afr, ahr, AF32);
    commitT(sB, bfr, bhr, BF32);
    __syncthreads();

    int cur = 0;
    for (int kt = 0; kt < K; kt += 32) {
        const int ktn = (kt + 32 < K) ? kt + 32 : 0;
        loadT(Ag, ktn, afr, ahr, AF32);
        loadT(Bg, ktn, bfr, bhr, BF32);

        const short* sAc = sA + cur * 4096;
        const short* sBc = sB + cur * 4096;
        s16x8 aF[2], bF[4];
#pragma unroll
        for (int i = 0; i < 2; ++i)
            aF[i] = *(const s16x8*)(sAc + (wm + i * 16 + l15) * 32 + quad * 8);
#pragma unroll
        for (int j = 0; j < 4; ++j)
            bF[j] = *(const s16x8*)(sBc + (wn + j * 16 + l15) * 32 + quad * 8);
#pragma unroll
        for (int i = 0; i < 2; ++i)
#pragma unroll
            for (int j = 0; j < 4; ++j)
                acc[i][j] = __builtin_amdgcn_mfma_f32_16x16x32_bf16(aF[i], bF[j], acc[i][j], 0, 0, 0);

        // commit tile t+1 into the idle buffer; single barrier
        commitT(sA + (cur ^ 1) * 4096, afr, ahr, AF32);
        commitT(sB + (cur ^ 1) * 4096, bfr, bhr, BF32);
        __syncthreads();
        cur ^= 1;
    }
}

// ---------------------------------------------------------------------------
// Kernel 1: fused QKV projection (fp32 in -> bf16 out).
// z=0: q scaled by 0.125*log2(e)  (flash uses exp2 -> native v_exp_f32)
// z=1: k -> (BH,S,HD).  z=2: v written DIRECTLY TRANSPOSED -> vt (BH,HD,S)
// Grid (64,4,3): M-tile fastest -> blocks sharing an A-tile are 64 apart
// = same XCD (64 mod 8 == 0) -> A fetched once per XCD, not 4x.
// ---------------------------------------------------------------------------
__global__ __launch_bounds__(512, 4) void qkv_proj(const float* __restrict__ query,
                                                   const float* __restrict__ key,
                                                   const float* __restrict__ value,
                                                   const float* __restrict__ W,
                                                   const float* __restrict__ bias,
                                                   short* __restrict__ q,
                                                   short* __restrict__ k,
                                                   short* __restrict__ vt)
{
    __shared__ __align__(16) short sA[2 * 4096], sB[2 * 4096];
    const int z = blockIdx.z;
    const float* X  = (z == 0) ? query : (z == 1) ? key : value;
    const float* Wz = W    + (z == 2 ? (size_t)1024 * EMB : 0);
    const float* bz = bias + (z == 2 ? 1024 : 0);
    const float scale = (z == 0) ? 0.125f * 1.44269504f : 1.0f;

    const int blockM = blockIdx.x * 128, blockN = blockIdx.y * 128;

    f32x4 acc[2][4];
#pragma unroll
    for (int i = 0; i < 2; ++i)
#pragma unroll
        for (int j = 0; j < 4; ++j)
            acc[i][j] = (f32x4){0.f, 0.f, 0.f, 0.f};

    gemm_mainloop<1, 1>(X + (size_t)blockM * EMB, Wz + (size_t)blockN * EMB,
                        sA, sB, acc, EMB);

    const int tid = threadIdx.x, lane = tid & 63, wv = tid >> 6;
    const int l15 = lane & 15, quad = lane >> 4;
    const int wm = (wv >> 1) * 32, wn = (wv & 1) * 64;

#pragma unroll
    for (int j = 0; j < 4; ++j) {
        int col = blockN + wn + j * 16 + l15;
        float bval = bz[col];
        int h = col >> 6, hd = col & 63;
#pragma unroll
        for (int i = 0; i < 2; ++i) {
#pragma unroll
            for (int r = 0; r < 4; ++r) {
                int row = blockM + wm + i * 16 + quad * 4 + r;
                int s = row >> 2, b = row & 3;
                float val = (acc[i][j][r] + bval) * scale;
                int bh = b * 8 + h;
                if (z == 2) {
                    vt[((size_t)(bh * 64 + hd)) * 2048 + s] = f2bf(val);
                } else {
                    short* dst = (z == 0) ? q : k;
                    dst[((size_t)(bh * 2048 + s)) * 64 + hd] = f2bf(val);
                }
            }
        }
    }
}

// ---------------------------------------------------------------------------
// Kernel 2 (v7): flash attention — V LDS-FREE.
//  - V fragments are contiguous 16B/lane in the vt (BH,HD,S) layout, and
//    the working set (8KB tile, shared by the block's 4 waves; 512KB per bh
//    pinned to one XCD's L2) is cache-resident. So PV reads V straight from
//    global into 8 regs at iter top; QK^T + softmax hides the L1/L2 latency.
//    LDS instrs/wave/iter: 20 -> 10. LDS footprint 36.9KB -> 18.4KB.
//  - K stays LDS (bit-permuted rows so QK^T output lands in K=32 A-fragment
//    order for PV; full-rate 16x16x32 PV, zero cross-lane traffic).
//  - Double-buffered sK, ONE __syncthreads per 64-key tile.
// Q pre-scaled by log2(e)/8 so p = exp2(s') (native v_exp_f32).
// ---------------------------------------------------------------------------
__global__ __launch_bounds__(256, 4) void flash_attn(const short* __restrict__ q,
                                                     const short* __restrict__ k,
                                                     const short* __restrict__ vt,
                                                     short* __restrict__ attn)
{
    __shared__ __align__(16) short sK[2][64 * 72];   // [buf][perm-key][hd]
    const int bh = blockIdx.x;            // fast grid dim -> XCD locality
    const int q0 = blockIdx.y * 64;
    const int tid = threadIdx.x, wv = tid >> 6, lane = tid & 63;
    const int l15 = lane & 15, quad = lane >> 4;

    const short* qp = q + ((size_t)(bh * 2048 + q0 + wv * 16 + l15)) * 64 + quad * 8;
    s16x8 qf0 = *(const s16x8*)qp;
    s16x8 qf1 = *(const s16x8*)(qp + 32);

    const short* kg = k  + (size_t)bh * 2048 * 64;   // + (kt+key)*64 + hd
    const short* vg = vt + (size_t)bh * 64 * 2048;   // + hd*2048 + kt + key
    // per-lane V fragment base: hd-row = l15 (within nt block), key = quad*8
    const short* vbase = vg + (size_t)l15 * 2048 + quad * 8;

    const int r0 = tid >> 3,          c0 = (tid & 7) * 8;
    const int r1 = (tid + 256) >> 3,  c1 = ((tid + 256) & 7) * 8;
    // permuted K rows (bijective bit shuffle; makes QK^T output == PV A-frag)
    const int p0 = (r0 & 35) | ((r0 & 24) >> 1) | ((r0 & 4) << 2);
    const int p1 = (r1 & 35) | ((r1 & 24) >> 1) | ((r1 & 4) << 2);

    f32x4 o[4];
    float ls[4];
#pragma unroll
    for (int i = 0; i < 4; ++i) { o[i] = (f32x4){0.f, 0.f, 0.f, 0.f}; ls[i] = 0.f; }

    // ---- prologue: stage K tile 0 into buffer 0 ----
    s16x8 ka = *(const s16x8*)(kg + (size_t)r0 * 64 + c0);
    s16x8 kb = *(const s16x8*)(kg + (size_t)r1 * 64 + c1);
    *(s16x8*)(sK[0] + p0 * 72 + c0) = ka;
    *(s16x8*)(sK[0] + p1 * 72 + c1) = kb;
    __syncthreads();

    int cur = 0;
    for (int kt = 0; kt < 2048; kt += 64) {
        // ---- issue V fragment loads for CURRENT tile (consumed by PV) ----
        s16x8 vf[8];
#pragma unroll
        for (int nt = 0; nt < 4; ++nt)
#pragma unroll
            for (int c = 0; c < 2; ++c)
                vf[nt * 2 + c] = *(const s16x8*)(vbase + (size_t)nt * 16 * 2048 + kt + c * 32);

        // ---- issue K staging loads for tile t+1 ----
        const int ktn = (kt + 64) & 2047;   // wraps on last iter (harmless)
        ka = *(const s16x8*)(kg + (size_t)(ktn + r0) * 64 + c0);
        kb = *(const s16x8*)(kg + (size_t)(ktn + r1) * 64 + c1);

        const short* Kc = sK[cur];

        // ---- S^T: mfma(A=K, B=Q) -> D[permkey=ct*16+quad*4+r][qrow=l15] ----
        f32x4 sc[4];
#pragma unroll
        for (int ct = 0; ct < 4; ++ct) {
            s16x8 kf0 = *(const s16x8*)(Kc + (ct * 16 + l15) * 72 + quad * 8);
            s16x8 kf1 = *(const s16x8*)(Kc + (ct * 16 + l15) * 72 + quad * 8 + 32);
            f32x4 c = (f32x4){0.f, 0.f, 0.f, 0.f};
            c = __builtin_amdgcn_mfma_f32_16x16x32_bf16(kf0, qf0, c, 0, 0, 0);
            c = __builtin_amdgcn_mfma_f32_16x16x32_bf16(kf1, qf1, c, 0, 0, 0);
            sc[ct] = c;
        }
        // ---- P = exp2(S); pack straight into K=32 A-fragments ----
        // pf[c][e] = P[qrow=l15][key32 = quad*8+e] of 32-block c (by row perm)
        s16x8 pf[2];
#pragma unroll
        for (int c = 0; c < 2; ++c)
#pragma unroll
            for (int h = 0; h < 2; ++h)
#pragma unroll
                for (int r = 0; r < 4; ++r) {
                    float p = EXP2F(sc[2 * c + h][r]);
                    ls[r] += p;
                    pf[c][h * 4 + r] = f2bf_fast(p);
                }
        // ---- PV: O[qrow][hd] += P-frag x V-frag (16x16x32, full rate) ----
#pragma unroll
        for (int nt = 0; nt < 4; ++nt)
#pragma unroll
            for (int c = 0; c < 2; ++c)
                o[nt] = __builtin_amdgcn_mfma_f32_16x16x32_bf16(pf[c], vf[nt * 2 + c], o[nt], 0, 0, 0);

        // ---- commit K tile t+1 into idle buffer; single barrier ----
        short* Kn = sK[cur ^ 1];
        *(s16x8*)(Kn + p0 * 72 + c0) = ka;
        *(s16x8*)(Kn + p1 * 72 + c1) = kb;
        __syncthreads();
        cur ^= 1;
    }

    // ---- row sums ----
    float s = ls[0] + ls[1] + ls[2] + ls[3];
    s += __shfl_xor(s, 16, 64);
    s += __shfl_xor(s, 32, 64);
    float sinv = 1.0f / s;
    float inv[4];
#pragma unroll
    for (int r = 0; r < 4; ++r)
        inv[r] = __shfl(sinv, quad * 20 + r, 64);

    // ---- epilogue ----
    const int b = bh >> 3, h = bh & 7;
#pragma unroll
    for (int r = 0; r < 4; ++r) {
        int srow = q0 + wv * 16 + quad * 4 + r;
#pragma unroll
        for (int nt = 0; nt < 4; ++nt)
            attn[(size_t)(srow * 4 + b) * 512 + h * 64 + nt * 16 + l15] = f2bf(o[nt][r] * inv[r]);
    }
}

// ---------------------------------------------------------------------------
// Kernel 3: output projection. A = attn (bf16 scratch), B = W (fp32), out FP32.
// Grid (64,4): M-tile fastest (same-XCD A-tile sharing). 512 threads ->
// 2 waves/SIMD at 1 block/CU; dbuf mainloop -> 1 barrier per K-step.
// ---------------------------------------------------------------------------
__global__ __launch_bounds__(512, 4) void out_proj(const short* __restrict__ attn,
                                                   const float* __restrict__ W,
                                                   const float* __restrict__ bias,
                                                   float* __restrict__ out)
{
    __shared__ __align__(16) short sA[2 * 4096], sB[2 * 4096];
    const int blockM = blockIdx.x * 128, blockN = blockIdx.y * 128;

    f32x4 acc[2][4];
#pragma unroll
    for (int i = 0; i < 2; ++i)
#pragma unroll
        for (int j = 0; j < 4; ++j)
            acc[i][j] = (f32x4){0.f, 0.f, 0.f, 0.f};

    gemm_mainloop<0, 1>(attn + (size_t)blockM * EMB, W + (size_t)blockN * EMB,
                        sA, sB, acc, EMB);

    const int tid = threadIdx.x, lane = tid & 63, wv = tid >> 6;
    const int l15 = lane & 15, quad = lane >> 4;
    const int wm = (wv >> 1) * 32, wn = (wv & 1) * 64;

#pragma unroll
    for (int j = 0; j < 4; ++j) {
        int col = blockN + wn + j * 16 + l15;
        float bval = bias[col];
#pragma unroll
        for (int i = 0; i < 2; ++i) {
#pragma unroll
            for (int r = 0; r < 4; ++r) {
                int row = blockM + wm + i * 16 + quad * 4 + r;
                out[(size_t)row * 512 + col] = acc[i][j][r] + bval;
            }
        }
    }
}

// ---------------------------------------------------------------------------
// Dtype contract: inputs FP32, output FP32. Internals bf16.
// 3 dispatches (transpose_v fused into qkv_proj's V epilogue):
//   qkv_proj:  fp32 inputs -> bf16 q,k (ws) + V^T directly into d_out
//   flash_attn: q, k, d_out(V^T) -> attn (ws)
//   out_proj:  attn + fp32 W_out -> d_out (fp32 final, overwrites V^T)
// ---------------------------------------------------------------------------
extern "C" void kernel_launch(void* const* d_in, const int* in_sizes, int n_in,
                              void* d_out, int out_size, void* d_ws, size_t ws_size,
                              hipStream_t stream)
{
    const float* query = (const float*)d_in[0];
    const float* key   = (const float*)d_in[1];
    const float* value = (const float*)d_in[2];
    const float* ipw   = (const float*)d_in[3];   // (1536, 512)
    const float* ipb   = (const float*)d_in[4];   // (1536,)
    const float* opw   = (const float*)d_in[5];   // (512, 512)
    const float* opb   = (const float*)d_in[6];   // (512,)
    float* out = (float*)d_out;

    const size_t NELEM = (size_t)MROWS * EMB;     // 4,194,304 elements
    short* q    = (short*)d_ws;
    short* k    = q + NELEM;
    short* attn = k + NELEM;
    short* vt   = (short*)d_out;                  // 16-bit scratch inside fp32 d_out

    qkv_proj  <<<dim3(64, 4, 3), 512, 0, stream>>>(query, key, value, ipw, ipb, q, k, vt);
    flash_attn<<<dim3(32, 32),   256, 0, stream>>>(q, k, vt, attn);
    out_proj  <<<dim3(64, 4),    512, 0, stream>>>(attn, opw, opb, out);
}

// Round 3
// 188.002 us; speedup vs baseline: 1.4325x; 1.4325x over previous
//
#include <hip/hip_runtime.h>
#include <hip/hip_bf16.h>

typedef __attribute__((ext_vector_type(8))) short s16x8;
typedef __attribute__((ext_vector_type(4))) short s16x4;
typedef __attribute__((ext_vector_type(4))) float f32x4;

#if __has_builtin(__builtin_amdgcn_exp2f)
#define EXP2F(x) __builtin_amdgcn_exp2f(x)
#else
#define EXP2F(x) exp2f(x)
#endif

#define S_LEN 2048
#define EMB   512
#define MROWS 8192   // S*B

__device__ __forceinline__ float bf2f(short x) {
    union { float f; unsigned u; } z; z.u = ((unsigned)(unsigned short)x) << 16; return z.f;
}
// RNE — epilogues only
__device__ __forceinline__ short f2bf(float f) {
    union { float f; unsigned u; } z; z.f = f;
    unsigned r = z.u + 0x7FFF + ((z.u >> 16) & 1);
    return (short)(r >> 16);
}
// fast round-half-away (2 VALU ops) — hot paths
__device__ __forceinline__ short f2bf_fast(float f) {
    union { float f; unsigned u; } z; z.f = f;
    return (short)((z.u + 0x8000u) >> 16);
}

// ---------------------------------------------------------------------------
// BT-GEMM mainloop (512 threads = 8 waves, 4x2 wave grid, wave tile 32x64):
// C[128x128] += A[128xK] * B[128xK]^T.  Double-buffered LDS, one barrier
// per K-step.  (proven v6 structure, unchanged)
// ---------------------------------------------------------------------------
template<int AF32, int BF32>
__device__ __forceinline__ void gemm_mainloop(const void* __restrict__ Ag,
                                              const void* __restrict__ Bg,
                                              short* sA, short* sB,
                                              f32x4 acc[2][4], int K)
{
    const int tid  = threadIdx.x;          // 0..511
    const int lane = tid & 63;
    const int wv   = tid >> 6;             // 0..7
    const int l15  = lane & 15, quad = lane >> 4;
    const int wm   = (wv >> 1) * 32, wn = (wv & 1) * 64;

    f32x4 afr[2], bfr[2];   // fp32 staging regs (2 x f32x4 per tile)
    s16x8 ahr, bhr;         // bf16 staging regs (1 x s16x8 per tile)

    auto loadT = [&](const void* G, int kt, f32x4* fr, s16x8& hr, int F32) {
        if (F32) {
#pragma unroll
            for (int p = 0; p < 2; ++p) {
                int c = tid + p * 512;     // 1024 chunks of 4 floats
                fr[p] = *(const f32x4*)((const float*)G + (size_t)(c >> 3) * K + kt + (c & 7) * 4);
            }
        } else {
            hr = *(const s16x8*)((const short*)G + (size_t)(tid >> 2) * K + kt + (tid & 3) * 8);
        }
    };
    auto commitT = [&](short* s, f32x4* fr, s16x8& hr, int F32) {
        if (F32) {
#pragma unroll
            for (int p = 0; p < 2; ++p) {
                int c = tid + p * 512;
                s16x4 o4;
                o4[0] = f2bf_fast(fr[p][0]); o4[1] = f2bf_fast(fr[p][1]);
                o4[2] = f2bf_fast(fr[p][2]); o4[3] = f2bf_fast(fr[p][3]);
                *(s16x4*)(s + c * 4) = o4;
            }
        } else {
            *(s16x8*)(s + tid * 8) = hr;
        }
    };

    // prologue: stage tile 0 into buffer 0
    loadT(Ag, 0, afr, ahr, AF32);
    loadT(Bg, 0, bfr, bhr, BF32);
    commitT(sA, afr, ahr, AF32);
    commitT(sB, bfr, bhr, BF32);
    __syncthreads();

    int cur = 0;
    for (int kt = 0; kt < K; kt += 32) {
        const int ktn = (kt + 32 < K) ? kt + 32 : 0;
        loadT(Ag, ktn, afr, ahr, AF32);
        loadT(Bg, ktn, bfr, bhr, BF32);

        const short* sAc = sA + cur * 4096;
        const short* sBc = sB + cur * 4096;
        s16x8 aF[2], bF[4];
#pragma unroll
        for (int i = 0; i < 2; ++i)
            aF[i] = *(const s16x8*)(sAc + (wm + i * 16 + l15) * 32 + quad * 8);
#pragma unroll
        for (int j = 0; j < 4; ++j)
            bF[j] = *(const s16x8*)(sBc + (wn + j * 16 + l15) * 32 + quad * 8);
#pragma unroll
        for (int i = 0; i < 2; ++i)
#pragma unroll
            for (int j = 0; j < 4; ++j)
                acc[i][j] = __builtin_amdgcn_mfma_f32_16x16x32_bf16(aF[i], bF[j], acc[i][j], 0, 0, 0);

        // commit tile t+1 into the idle buffer; single barrier
        commitT(sA + (cur ^ 1) * 4096, afr, ahr, AF32);
        commitT(sB + (cur ^ 1) * 4096, bfr, bhr, BF32);
        __syncthreads();
        cur ^= 1;
    }
}

// ---------------------------------------------------------------------------
// Kernel 1 (v8): fused QKV projection (fp32 in -> bf16 out).
// z=0: q scaled by 0.125*log2(e).  z=1: k -> (BH,S,HD).
// z=2: v -> vt (BH,HD,S) transposed.
// NEW: epilogue stages the C-tile through LDS (reusing the 32KB GEMM
// buffers) in OUTPUT order, then stores 64B contiguous per thread.
// Old path was 32 scalar 2B scattered stores/thread (2B useful per 64B
// line for z=2) — the dominant cost of this kernel.
// ---------------------------------------------------------------------------
__global__ __launch_bounds__(512, 4) void qkv_proj(const float* __restrict__ query,
                                                   const float* __restrict__ key,
                                                   const float* __restrict__ value,
                                                   const float* __restrict__ W,
                                                   const float* __restrict__ bias,
                                                   short* __restrict__ q,
                                                   short* __restrict__ k,
                                                   short* __restrict__ vt)
{
    __shared__ __align__(16) short smem[16384];   // GEMM dbuf; reused by epilogue
    short* sA = smem;            // 2 x 4096
    short* sB = smem + 8192;     // 2 x 4096

    const int z = blockIdx.z;
    const float* X  = (z == 0) ? query : (z == 1) ? key : value;
    const float* Wz = W    + (z == 2 ? (size_t)1024 * EMB : 0);
    const float* bz = bias + (z == 2 ? 1024 : 0);
    const float scale = (z == 0) ? 0.125f * 1.44269504f : 1.0f;

    const int blockM = blockIdx.x * 128, blockN = blockIdx.y * 128;

    f32x4 acc[2][4];
#pragma unroll
    for (int i = 0; i < 2; ++i)
#pragma unroll
        for (int j = 0; j < 4; ++j)
            acc[i][j] = (f32x4){0.f, 0.f, 0.f, 0.f};

    gemm_mainloop<1, 1>(X + (size_t)blockM * EMB, Wz + (size_t)blockN * EMB,
                        sA, sB, acc, EMB);

    const int tid = threadIdx.x, lane = tid & 63, wv = tid >> 6;
    const int l15 = lane & 15, quad = lane >> 4;
    const int wm = (wv >> 1) * 32, wn = (wv & 1) * 64;

    // ---- stage C-tile into LDS in output order (bf16, RNE) ----
    // z=0/1 layout: [b][hL][s'][hd]  (idx = ((b*2+hL)*32+s')*64+hd)
    // z=2  layout: [b][hL][hd][s']  (idx = ((b*2+hL)*64+hd)*32+s')
#pragma unroll
    for (int j = 0; j < 4; ++j) {
        int colL = wn + j * 16 + l15;          // 0..127
        float bval = bz[blockN + colL];
        int hL = colL >> 6, hd = colL & 63;
#pragma unroll
        for (int i = 0; i < 2; ++i) {
#pragma unroll
            for (int r = 0; r < 4; ++r) {
                int rowL = wm + i * 16 + quad * 4 + r;   // 0..127
                int b = rowL & 3, sp = rowL >> 2;
                float val = (acc[i][j][r] + bval) * scale;
                int idx = (z == 2) ? (((b * 2 + hL) * 64 + hd) * 32 + sp)
                                   : (((b * 2 + hL) * 32 + sp) * 64 + hd);
                smem[idx] = f2bf(val);
            }
        }
    }
    __syncthreads();

    // ---- coalesced stores: thread t owns shorts [t*32, t*32+32) of smem ----
    const s16x8* src = (const s16x8*)(smem + tid * 32);
    if (z == 2) {
        // row R = tid: chunk=R>>6 -> (b,hL), hd=R&63; 64B contiguous in s
        int b = tid >> 7, hL = (tid >> 6) & 1, hd = tid & 63;
        int h = (blockN >> 6) + hL;
        short* dst = vt + ((size_t)(b * 8 + h) * 64 + hd) * 2048 + (blockM >> 2);
#pragma unroll
        for (int u = 0; u < 4; ++u) ((s16x8*)dst)[u] = src[u];
    } else {
        // chunk = tid>>6 -> (b,hL); s' = (tid>>1)&31; hd-half = (tid&1)*32
        int b = tid >> 7, hL = (tid >> 6) & 1;
        int sp = (tid >> 1) & 31, hdh = (tid & 1) * 32;
        int h = (blockN >> 6) + hL;
        short* dstp = (z == 0) ? q : k;
        short* dst = dstp + ((size_t)(b * 8 + h) * 2048 + (blockM >> 2) + sp) * 64 + hdh;
#pragma unroll
        for (int u = 0; u < 4; ++u) ((s16x8*)dst)[u] = src[u];
    }
}

// ---------------------------------------------------------------------------
// Kernel 2 (v8): flash attention — v6 structure (LDS K+V, bit-permuted K
// rows -> full-rate K=32 PV, dbuf, 1 barrier/iter) with QBLK=32 per wave.
// K/V fragment reads from LDS are IDENTICAL for both Q sub-tiles, so
// doubling the Q rows per wave halves LDS instructions per MFMA — round-1
// analysis showed the LDS pipe ~95% busy was the wall.  Grid y: 32 -> 16
// (512 blocks, 2 blocks/CU, 2 waves/SIMD).
// Q pre-scaled by log2(e)/8 so p = exp2(s') (native v_exp_f32).
// ---------------------------------------------------------------------------
__global__ __launch_bounds__(256, 2) void flash_attn(const short* __restrict__ q,
                                                     const short* __restrict__ k,
                                                     const short* __restrict__ vt,
                                                     short* __restrict__ attn)
{
    __shared__ __align__(16) short sK[2][64 * 72];   // [buf][perm-key][hd]
    __shared__ __align__(16) short sV[2][64 * 72];   // [buf][hd][key]
    const int bh = blockIdx.x;            // fast grid dim -> XCD locality
    const int q0 = blockIdx.y * 128;
    const int tid = threadIdx.x, wv = tid >> 6, lane = tid & 63;
    const int l15 = lane & 15, quad = lane >> 4;

    // Q fragments: 2 sub-tiles (qr) x 2 K-halves
    s16x8 qf[2][2];
#pragma unroll
    for (int qr = 0; qr < 2; ++qr) {
        const short* qp = q + ((size_t)(bh * 2048 + q0 + wv * 32 + qr * 16 + l15)) * 64 + quad * 8;
        qf[qr][0] = *(const s16x8*)qp;
        qf[qr][1] = *(const s16x8*)(qp + 32);
    }

    const short* kg = k  + (size_t)bh * 2048 * 64;   // + (kt+key)*64 + hd
    const short* vg = vt + (size_t)bh * 64 * 2048;   // + hd*2048 + kt + key

    const int r0 = tid >> 3,          c0 = (tid & 7) * 8;
    const int r1 = (tid + 256) >> 3,  c1 = ((tid + 256) & 7) * 8;
    // permuted K rows (bijective bit shuffle; makes QK^T output == PV A-frag)
    const int p0 = (r0 & 35) | ((r0 & 24) >> 1) | ((r0 & 4) << 2);
    const int p1 = (r1 & 35) | ((r1 & 24) >> 1) | ((r1 & 4) << 2);

    f32x4 o[2][4];
    float ls[2][4];
#pragma unroll
    for (int qr = 0; qr < 2; ++qr)
#pragma unroll
        for (int i = 0; i < 4; ++i) { o[qr][i] = (f32x4){0.f, 0.f, 0.f, 0.f}; ls[qr][i] = 0.f; }

    // ---- prologue: stage tile 0 into buffer 0 ----
    s16x8 ka = *(const s16x8*)(kg + (size_t)r0 * 64 + c0);
    s16x8 kb = *(const s16x8*)(kg + (size_t)r1 * 64 + c1);
    s16x8 va = *(const s16x8*)(vg + (size_t)r0 * 2048 + c0);
    s16x8 vb = *(const s16x8*)(vg + (size_t)r1 * 2048 + c1);
    *(s16x8*)(sK[0] + p0 * 72 + c0) = ka;
    *(s16x8*)(sK[0] + p1 * 72 + c1) = kb;
    *(s16x8*)(sV[0] + r0 * 72 + c0) = va;
    *(s16x8*)(sV[0] + r1 * 72 + c1) = vb;
    __syncthreads();

    int cur = 0;
    for (int kt = 0; kt < 2048; kt += 64) {
        const int ktn = (kt + 64) & 2047;   // wraps on last iter (harmless)
        ka = *(const s16x8*)(kg + (size_t)(ktn + r0) * 64 + c0);
        kb = *(const s16x8*)(kg + (size_t)(ktn + r1) * 64 + c1);
        va = *(const s16x8*)(vg + (size_t)r0 * 2048 + ktn + c0);
        vb = *(const s16x8*)(vg + (size_t)r1 * 2048 + ktn + c1);

        const short* Kc = sK[cur];
        const short* Vc = sV[cur];

        // ---- S^T: mfma(A=K, B=Q) -> D[permkey=ct*16+quad*4+r][qrow=l15] ----
        // K fragments shared across both Q sub-tiles.
        f32x4 sc[2][4];
#pragma unroll
        for (int ct = 0; ct < 4; ++ct) {
            s16x8 kf0 = *(const s16x8*)(Kc + (ct * 16 + l15) * 72 + quad * 8);
            s16x8 kf1 = *(const s16x8*)(Kc + (ct * 16 + l15) * 72 + quad * 8 + 32);
#pragma unroll
            for (int qr = 0; qr < 2; ++qr) {
                f32x4 c = (f32x4){0.f, 0.f, 0.f, 0.f};
                c = __builtin_amdgcn_mfma_f32_16x16x32_bf16(kf0, qf[qr][0], c, 0, 0, 0);
                c = __builtin_amdgcn_mfma_f32_16x16x32_bf16(kf1, qf[qr][1], c, 0, 0, 0);
                sc[qr][ct] = c;
            }
        }
        // ---- P = exp2(S); pack straight into K=32 A-fragments ----
        s16x8 pf[2][2];
#pragma unroll
        for (int qr = 0; qr < 2; ++qr)
#pragma unroll
            for (int c = 0; c < 2; ++c)
#pragma unroll
                for (int h = 0; h < 2; ++h)
#pragma unroll
                    for (int r = 0; r < 4; ++r) {
                        float p = EXP2F(sc[qr][2 * c + h][r]);
                        ls[qr][r] += p;
                        pf[qr][c][h * 4 + r] = f2bf_fast(p);
                    }
        // ---- PV: O[qrow][hd] += P-frag x V-frag; V frags shared by qr ----
#pragma unroll
        for (int nt = 0; nt < 4; ++nt)
#pragma unroll
            for (int c = 0; c < 2; ++c) {
                s16x8 vf = *(const s16x8*)(Vc + (nt * 16 + l15) * 72 + c * 32 + quad * 8);
#pragma unroll
                for (int qr = 0; qr < 2; ++qr)
                    o[qr][nt] = __builtin_amdgcn_mfma_f32_16x16x32_bf16(pf[qr][c], vf, o[qr][nt], 0, 0, 0);
            }
        // ---- commit tile t+1 into idle buffer; single barrier ----
        short* Kn = sK[cur ^ 1];
        short* Vn = sV[cur ^ 1];
        *(s16x8*)(Kn + p0 * 72 + c0) = ka;
        *(s16x8*)(Kn + p1 * 72 + c1) = kb;
        *(s16x8*)(Vn + r0 * 72 + c0) = va;
        *(s16x8*)(Vn + r1 * 72 + c1) = vb;
        __syncthreads();
        cur ^= 1;
    }

    // ---- row sums + epilogue, per Q sub-tile ----
    const int b = bh >> 3, h = bh & 7;
#pragma unroll
    for (int qr = 0; qr < 2; ++qr) {
        float s = ls[qr][0] + ls[qr][1] + ls[qr][2] + ls[qr][3];
        s += __shfl_xor(s, 16, 64);
        s += __shfl_xor(s, 32, 64);
        float sinv = 1.0f / s;
        float inv[4];
#pragma unroll
        for (int r = 0; r < 4; ++r)
            inv[r] = __shfl(sinv, quad * 20 + r, 64);
#pragma unroll
        for (int r = 0; r < 4; ++r) {
            int srow = q0 + wv * 32 + qr * 16 + quad * 4 + r;
#pragma unroll
            for (int nt = 0; nt < 4; ++nt)
                attn[(size_t)(srow * 4 + b) * 512 + h * 64 + nt * 16 + l15] = f2bf(o[qr][nt][r] * inv[r]);
        }
    }
}

// ---------------------------------------------------------------------------
// Kernel 3: output projection. A = attn (bf16 scratch), B = W (fp32), out FP32.
// Stores are 64B-segment coalesced already (fp32 row-major, l15 = col).
// ---------------------------------------------------------------------------
__global__ __launch_bounds__(512, 4) void out_proj(const short* __restrict__ attn,
                                                   const float* __restrict__ W,
                                                   const float* __restrict__ bias,
                                                   float* __restrict__ out)
{
    __shared__ __align__(16) short sA[2 * 4096], sB[2 * 4096];
    const int blockM = blockIdx.x * 128, blockN = blockIdx.y * 128;

    f32x4 acc[2][4];
#pragma unroll
    for (int i = 0; i < 2; ++i)
#pragma unroll
        for (int j = 0; j < 4; ++j)
            acc[i][j] = (f32x4){0.f, 0.f, 0.f, 0.f};

    gemm_mainloop<0, 1>(attn + (size_t)blockM * EMB, W + (size_t)blockN * EMB,
                        sA, sB, acc, EMB);

    const int tid = threadIdx.x, lane = tid & 63, wv = tid >> 6;
    const int l15 = lane & 15, quad = lane >> 4;
    const int wm = (wv >> 1) * 32, wn = (wv & 1) * 64;

#pragma unroll
    for (int j = 0; j < 4; ++j) {
        int col = blockN + wn + j * 16 + l15;
        float bval = bias[col];
#pragma unroll
        for (int i = 0; i < 2; ++i) {
#pragma unroll
            for (int r = 0; r < 4; ++r) {
                int row = blockM + wm + i * 16 + quad * 4 + r;
                out[(size_t)row * 512 + col] = acc[i][j][r] + bval;
            }
        }
    }
}

// ---------------------------------------------------------------------------
// Dtype contract: inputs FP32, output FP32. Internals bf16.
// 3 dispatches:
//   qkv_proj:  fp32 inputs -> bf16 q,k (ws) + V^T directly into d_out
//   flash_attn: q, k, d_out(V^T) -> attn (ws)
//   out_proj:  attn + fp32 W_out -> d_out (fp32 final, overwrites V^T)
// ---------------------------------------------------------------------------
extern "C" void kernel_launch(void* const* d_in, const int* in_sizes, int n_in,
                              void* d_out, int out_size, void* d_ws, size_t ws_size,
                              hipStream_t stream)
{
    const float* query = (const float*)d_in[0];
    const float* key   = (const float*)d_in[1];
    const float* value = (const float*)d_in[2];
    const float* ipw   = (const float*)d_in[3];   // (1536, 512)
    const float* ipb   = (const float*)d_in[4];   // (1536,)
    const float* opw   = (const float*)d_in[5];   // (512, 512)
    const float* opb   = (const float*)d_in[6];   // (512,)
    float* out = (float*)d_out;

    const size_t NELEM = (size_t)MROWS * EMB;     // 4,194,304 elements
    short* q    = (short*)d_ws;
    short* k    = q + NELEM;
    short* attn = k + NELEM;
    short* vt   = (short*)d_out;                  // 16-bit scratch inside fp32 d_out

    qkv_proj  <<<dim3(64, 4, 3), 512, 0, stream>>>(query, key, value, ipw, ipb, q, k, vt);
    flash_attn<<<dim3(32, 16),   256, 0, stream>>>(q, k, vt, attn);
    out_proj  <<<dim3(64, 4),    512, 0, stream>>>(attn, opw, opb, out);
}